// Round 7
// baseline (108.844 us; speedup 1.0000x reference)
//
#include <hip/hip_runtime.h>

#define NBATCH 256

typedef __attribute__((ext_vector_type(8)))  short bf16x8;
typedef __attribute__((ext_vector_type(16))) float f32x16;

__device__ __forceinline__ unsigned short f2b(float f) {
    unsigned u = __float_as_uint(f);
    u = (u + 0x7fffu + ((u >> 16) & 1u)) >> 16;
    return (unsigned short)u;
}
__device__ __forceinline__ float b2f(unsigned short h) {
    return __uint_as_float(((unsigned)h) << 16);
}
__device__ __forceinline__ void async16(const void* g, void* l) {
    __builtin_amdgcn_global_load_lds((const __attribute__((address_space(1))) unsigned int*)g,
                                     (__attribute__((address_space(3))) unsigned int*)l, 16, 0, 0);
}

// ---------------- fused prep kernel (x4 vectorized) ----------------
// blocks [0,512): W0 ; [512,1536): W1 ; [1536,2560): W2 ; [2560,3584): x
// W granule tiling for mfma_32x32x16 A-operand:
//   granule(rgg, kstep): lane = (o&31) + 32*khalf, khalf=(c>>3)&1, j=c&7
//   kstep = f*(CL/16) + (c>>4);  elem = ((rgg*NKL + kstep)*64 + lane)*8 + j
__global__ void prep_all(const float* __restrict__ x,
                         const float* __restrict__ W0,
                         const float* __restrict__ W1,
                         const float* __restrict__ W2,
                         unsigned short* __restrict__ x0t,
                         unsigned short* __restrict__ x0f,
                         unsigned short* __restrict__ Wp0,
                         unsigned short* __restrict__ Wp1,
                         unsigned short* __restrict__ Wp2)
{
    const int bid = blockIdx.x, tid = threadIdx.x;
    if (bid < 2560) {
        const float* W; unsigned short* Wp; int CLOG, KLOG, lbid;
        if (bid < 512)       { W = W0; Wp = Wp0; CLOG = 6; KLOG = 12; lbid = bid; }
        else if (bid < 1536) { W = W1; Wp = Wp1; CLOG = 7; KLOG = 13; lbid = bid - 512; }
        else                 { W = W2; Wp = Wp2; CLOG = 7; KLOG = 13; lbid = bid - 1536; }
        const int base = (lbid * 256 + tid) * 4;   // 4 consecutive k, same o
        const int NKL = 1 << (KLOG - 4);           // ksteps per rgg slice
        int o = base >> KLOG, k = base & ((1 << KLOG) - 1);
        int f = k >> CLOG, c = k & ((1 << CLOG) - 1);
        int rgg = o >> 5;
        int lane = (o & 31) + ((c >> 3) & 1) * 32;
        int kstep = f * (1 << (CLOG - 4)) + (c >> 4);
        int j0 = c & 7;                            // 0 or 4
        size_t dst = (((size_t)rgg * NKL + kstep) * 64 + lane) * 8 + j0;
        const float4 wv = *(const float4*)(W + base);
        *(ushort4*)(Wp + dst) = make_ushort4(f2b(wv.x), f2b(wv.y), f2b(wv.z), f2b(wv.w));
    } else {
        const int base = ((bid - 2560) * 256 + tid) * 4;   // 4 consecutive e
        int b = base >> 12, r = base & 4095, f = r >> 6, e0 = r & 63;
        const float4 xv = *(const float4*)(x + base);
        ushort4 v = make_ushort4(f2b(xv.x), f2b(xv.y), f2b(xv.z), f2b(xv.w));
        *(ushort4*)(x0f + b * 4096 + f * 64 + e0) = v;     // [b][f][e]
        x0t[b * 4096 + (e0 + 0) * 64 + f] = v.x;           // [b][e][f]
        x0t[b * 4096 + (e0 + 1) * 64 + f] = v.y;
        x0t[b * 4096 + (e0 + 2) * 64 + f] = v.z;
        x0t[b * 4096 + (e0 + 3) * 64 + f] = v.w;
    }
}

// ---------------- per-layer GEMM kernel (32x32x16 MFMA) ----------------
// grid 256 = 4 rgg (32 o-rows) x 64 sgg (4 samples); 512 thr, 8 waves.
// wave w: sample p = w&3 (s = sgg*4+p), kg = w>>2 (K-half by field).
// A (W slice) chunked/double-buffered in LDS; B (xk) VGPR-resident;
// x0 scales from per-sample LDS; cross-kg LDS reduction at layer end.
template <int CL, bool LAST>
__global__ __launch_bounds__(512, 2) void layer_k(
    const unsigned short* __restrict__ Wp,    // pre-tiled A
    const unsigned short* __restrict__ Bsrc,  // [b][e][c] rows of CL*2 bytes
    const unsigned short* __restrict__ x0f,   // [b][f][e]
    const float* __restrict__ Wa_l,
    unsigned short* __restrict__ xknext,      // [b][e][o] rows of 256B
    float* __restrict__ ybuf)                 // [256][4] this layer
{
    constexpr int NCS16 = CL / 16;            // cs chunks per field (4 or 8)
    constexpr int NK    = 64 * NCS16;         // total ksteps (both kg)
    constexpr int NKg   = NK / 2;             // per kg
    constexpr int NCH   = NKg / 16;           // chunks (16 ksteps/kg each)
    constexpr int FPC   = 16 / NCS16;         // fields per chunk
    extern __shared__ char sm[];
    char* smA = sm;                           // 2 x 32 KB chunk buffers
    char* smX = sm + 65536;                   // 4 x 8 KB per-sample x0f

    const int bid = blockIdx.x, tid = threadIdx.x;
    const int rgg = bid & 3, sgg = bid >> 2;
    const int lane = tid & 63, w = tid >> 6;
    const int p = w & 3, kg = w >> 2;
    const int s = sgg * 4 + p;
    const int l31 = lane & 31, khalf = lane >> 5;

    // stage 4 samples' x0f (8 KB each)
#pragma unroll
    for (int q = 0; q < 4; ++q)
        async16((const char*)x0f + (size_t)(sgg * 4 + q) * 8192 + tid * 16,
                smX + q * 8192 + w * 1024);

    // B granules: field-invariant, VGPR-resident. granule(cs, t):
    // lane: col e' = l31 + t*32, c0 = cs*16 + khalf*8
    bf16x8 bq[NCS16][2];
    {
        const char* Bb = (const char*)Bsrc + ((size_t)s * 64 + l31) * (CL * 2) + khalf * 16;
#pragma unroll
        for (int cs = 0; cs < NCS16; ++cs)
#pragma unroll
            for (int t = 0; t < 2; ++t)
                bq[cs][t] = *(const bf16x8*)(Bb + t * 32 * (CL * 2) + cs * 32);
    }

    const char* Ab = (const char*)Wp + (size_t)rgg * NK * 1024;
    auto stage = [&](int ch, int buf) {
#pragma unroll
        for (int i = 0; i < 4; ++i) {
            const int g = i * 8 + w;                       // 0..31, wave-uniform
            const int ksg = (i < 2) ? (ch * 16 + g) : (NKg + ch * 16 + (g - 16));
            async16(Ab + (size_t)ksg * 1024 + lane * 16,
                    smA + buf * 32768 + g * 1024);
        }
    };
    stage(0, 0);
    __syncthreads();

    const unsigned short* XS = (const unsigned short*)(smX + p * 8192);
    const f32x16 ZERO = {0.f};
    f32x16 acc[2] = {ZERO, ZERO};
    f32x16 ae[2], ao[2];

    for (int ch = 0; ch < NCH; ++ch) {
        const int cur = ch & 1;
        if (ch + 1 < NCH) stage(ch + 1, cur ^ 1);
#pragma unroll
        for (int cs = 0; cs < NCS16; ++cs)
            asm volatile("" :: "v"(bq[cs][0]), "v"(bq[cs][1]));
        const char* Abuf = smA + cur * 32768 + kg * 16384 + lane * 16;
#pragma unroll
        for (int fi = 0; fi < FPC; ++fi) {
            const int fg = kg * 32 + ch * FPC + fi;
            const float sv0 = b2f(XS[fg * 64 + l31]);
            const float sv1 = b2f(XS[fg * 64 + 32 + l31]);
#pragma unroll
            for (int cs = 0; cs < NCS16; ++cs) {
                const bf16x8 a = *(const bf16x8*)(Abuf + (fi * NCS16 + cs) * 1024);
                if ((cs & 1) == 0) {
                    ae[0] = __builtin_amdgcn_mfma_f32_32x32x16_bf16(a, bq[cs][0], (cs == 0) ? ZERO : ae[0], 0, 0, 0);
                    ae[1] = __builtin_amdgcn_mfma_f32_32x32x16_bf16(a, bq[cs][1], (cs == 0) ? ZERO : ae[1], 0, 0, 0);
                } else {
                    ao[0] = __builtin_amdgcn_mfma_f32_32x32x16_bf16(a, bq[cs][0], (cs == 1) ? ZERO : ao[0], 0, 0, 0);
                    ao[1] = __builtin_amdgcn_mfma_f32_32x32x16_bf16(a, bq[cs][1], (cs == 1) ? ZERO : ao[1], 0, 0, 0);
                }
            }
#pragma unroll
            for (int t = 0; t < 2; ++t) {
                const f32x16 sf = (t == 0)
                    ? f32x16{sv0,sv0,sv0,sv0,sv0,sv0,sv0,sv0,sv0,sv0,sv0,sv0,sv0,sv0,sv0,sv0}
                    : f32x16{sv1,sv1,sv1,sv1,sv1,sv1,sv1,sv1,sv1,sv1,sv1,sv1,sv1,sv1,sv1,sv1};
                acc[t] += (ae[t] + ao[t]) * sf;
            }
        }
        __syncthreads();
    }

    // ---- cross-kg reduction (reuse smA) ----
    if (kg == 1) {
#pragma unroll
        for (int t = 0; t < 2; ++t)
            *(f32x16*)(smA + p * 8192 + lane * 128 + t * 64) = acc[t];
    }
    __syncthreads();
    if (kg == 0) {
#pragma unroll
        for (int t = 0; t < 2; ++t)
            acc[t] += *(const f32x16*)(smA + p * 8192 + lane * 128 + t * 64);

        // epilogue: relu, y-partial, xknext write
        float ypart = 0.f;
#pragma unroll
        for (int t = 0; t < 2; ++t) {
            const int ecol = l31 + t * 32;
#pragma unroll
            for (int q = 0; q < 4; ++q) {
                const int o0 = rgg * 32 + 8 * q + 4 * khalf;
                float v0 = fmaxf(acc[t][q * 4 + 0], 0.f);
                float v1 = fmaxf(acc[t][q * 4 + 1], 0.f);
                float v2 = fmaxf(acc[t][q * 4 + 2], 0.f);
                float v3 = fmaxf(acc[t][q * 4 + 3], 0.f);
                ypart = fmaf(Wa_l[o0 + 0], v0, ypart);
                ypart = fmaf(Wa_l[o0 + 1], v1, ypart);
                ypart = fmaf(Wa_l[o0 + 2], v2, ypart);
                ypart = fmaf(Wa_l[o0 + 3], v3, ypart);
                if (!LAST) {
                    unsigned lo = (unsigned)f2b(v0) | ((unsigned)f2b(v1) << 16);
                    unsigned hi = (unsigned)f2b(v2) | ((unsigned)f2b(v3) << 16);
                    *(uint2*)((char*)xknext + (((size_t)s * 64 + ecol) * 128 + o0) * 2)
                        = make_uint2(lo, hi);
                }
            }
        }
#pragma unroll
        for (int off = 32; off >= 1; off >>= 1)
            ypart += __shfl_down(ypart, off, 64);
        if (lane == 0) ybuf[s * 4 + rgg] = ypart;
    }
}

__global__ void finalize_k(const float* __restrict__ ybuf, float* __restrict__ y) {
    const int b = threadIdx.x;
    float sum = 0.f;
#pragma unroll
    for (int l = 0; l < 3; ++l)
#pragma unroll
        for (int r = 0; r < 4; ++r)
            sum += ybuf[l * 1024 + b * 4 + r];
    y[b] = sum;
}

extern "C" void kernel_launch(void* const* d_in, const int* in_sizes, int n_in,
                              void* d_out, int out_size, void* d_ws, size_t ws_size,
                              hipStream_t stream) {
    const float* x  = (const float*)d_in[0];
    const float* W0 = (const float*)d_in[1];
    const float* W1 = (const float*)d_in[2];
    const float* W2 = (const float*)d_in[3];
    const float* Wa = (const float*)d_in[4];
    float* y = (float*)d_out;

    char* ws = (char*)d_ws;
    unsigned short* Wp0  = (unsigned short*)(ws + 0x000000);   // 1MB (+pad)
    unsigned short* Wp1  = (unsigned short*)(ws + 0x110000);   // 2MB (+pad)
    unsigned short* Wp2  = (unsigned short*)(ws + 0x320000);   // 2MB (+pad)
    unsigned short* x0t  = (unsigned short*)(ws + 0x530000);   // 2MB
    unsigned short* x0f  = (unsigned short*)(ws + 0x730000);   // 2MB
    unsigned short* xkA  = (unsigned short*)(ws + 0x930000);   // 4MB
    unsigned short* xkB  = (unsigned short*)(ws + 0xD30000);   // 4MB
    float*          ybuf = (float*)(ws + 0x1130000);           // 12KB

    hipLaunchKernelGGL(prep_all, dim3(3584), dim3(256), 0, stream,
                       x, W0, W1, W2, x0t, x0f, Wp0, Wp1, Wp2);

    hipFuncSetAttribute((const void*)layer_k<64, false>,
                        hipFuncAttributeMaxDynamicSharedMemorySize, 98304);
    hipFuncSetAttribute((const void*)layer_k<128, false>,
                        hipFuncAttributeMaxDynamicSharedMemorySize, 98304);
    hipFuncSetAttribute((const void*)layer_k<128, true>,
                        hipFuncAttributeMaxDynamicSharedMemorySize, 98304);

    hipLaunchKernelGGL((layer_k<64, false>), dim3(256), dim3(512), 98304, stream,
                       Wp0, x0t, x0f, Wa + 0, xkA, ybuf + 0);
    hipLaunchKernelGGL((layer_k<128, false>), dim3(256), dim3(512), 98304, stream,
                       Wp1, xkA, x0f, Wa + 128, xkB, ybuf + 1024);
    hipLaunchKernelGGL((layer_k<128, true>), dim3(256), dim3(512), 98304, stream,
                       Wp2, xkB, x0f, Wa + 256, xkA, ybuf + 2048);

    hipLaunchKernelGGL(finalize_k, dim3(1), dim3(256), 0, stream, ybuf, y);
}